// Round 2
// baseline (736.876 us; speedup 1.0000x reference)
//
#include <hip/hip_runtime.h>
#include <hip/hip_bf16.h>
#include <stdint.h>

typedef __hip_bfloat16 bf16;
typedef __attribute__((ext_vector_type(8))) short bf16x8;
typedef __attribute__((ext_vector_type(4))) float f32x4;
typedef __attribute__((ext_vector_type(16))) float f32x16;
typedef unsigned int u32;

static constexpr int Bsz = 4, S = 2048, D = 1024, E = 8, F = 4096, NH = 16, HD = 64;
static constexpr int TOK = Bsz * S;          // 8192 tokens
static constexpr int SLOTS = TOK + E * 256;  // 10240 padded routing slots (256-aligned experts)

#define DEV __device__ __forceinline__

DEV void async16(const bf16* g, bf16* l) {
  __builtin_amdgcn_global_load_lds((const __attribute__((address_space(1))) u32*)g,
                                   (__attribute__((address_space(3))) u32*)l, 16, 0, 0);
}

DEV u32 lds_off(const bf16* p) {
  return (u32)(uintptr_t)(__attribute__((address_space(3))) bf16*)p;
}

DEV bf16x8 dsr128(u32 addr) {  // asm ds_read: invisible to LDS alias analysis
  bf16x8 d;
  asm volatile("ds_read_b128 %0, %1" : "=v"(d) : "v"(addr));
  return d;
}

// gelu(x) = 0.5x(1+tanh(z)) = x * sigmoid(2z)
DEV float gelu_fast(float x) {
  const float z = 0.7978845608028654f * (x + 0.044715f * x * x * x);
  return x / (1.f + __expf(-2.f * z));
}

// ---------------- small kernels ----------------

// fp32 [R][C] -> bf16 [C][R], 64x64 tiles: 16B/lane coalesced on BOTH sides
__global__ void cvt_transpose(const float* __restrict__ in, bf16* __restrict__ out, int R, int C) {
  __shared__ float t[64][65];
  const size_t zoff = (size_t)blockIdx.z * R * C;
  const int c0 = blockIdx.x * 64, r0 = blockIdx.y * 64;
  const int tid = threadIdx.x;
  const int lrow = tid >> 4, lcol = (tid & 15) * 4;
#pragma unroll
  for (int p = 0; p < 4; ++p) {
    const int r = lrow + p * 16;
    const float4 v = *(const float4*)(in + zoff + (size_t)(r0 + r) * C + c0 + lcol);
    t[r][lcol] = v.x; t[r][lcol + 1] = v.y; t[r][lcol + 2] = v.z; t[r][lcol + 3] = v.w;
  }
  __syncthreads();
  const int ow = tid >> 3, je = (tid & 7) * 8;
#pragma unroll
  for (int p = 0; p < 2; ++p) {
    const int oc = ow + p * 32;
    union { bf16x8 v; bf16 b[8]; } o8;
#pragma unroll
    for (int j = 0; j < 8; ++j) o8.b[j] = __float2bfloat16(t[je + j][oc]);
    *(bf16x8*)(out + zoff + (size_t)(c0 + oc) * R + r0 + je) = o8.v;
  }
}

__global__ void rope_tables(float* __restrict__ cosT, float* __restrict__ sinT) {
  const int s = blockIdx.x * 2 + (threadIdx.x >> 5);
  const int i = threadIdx.x & 31;
  const float inv_freq = powf(10000.f, -(float)i / 32.f);
  const float ang = (float)s * inv_freq;
  cosT[s * 32 + i] = cosf(ang);
  sinT[s * 32 + i] = sinf(ang);
}

__global__ void rmsnorm_k(const float* __restrict__ x, const float* __restrict__ w, bf16* __restrict__ out) {
  const size_t row = blockIdx.x;
  const int tid = threadIdx.x;
  const float4 v = *(const float4*)(x + row * D + tid * 4);
  float ss = v.x * v.x + v.y * v.y + v.z * v.z + v.w * v.w;
#pragma unroll
  for (int off = 1; off < 64; off <<= 1) ss += __shfl_xor(ss, off);
  __shared__ float red[4];
  if ((tid & 63) == 0) red[tid >> 6] = ss;
  __syncthreads();
  const float inv = rsqrtf((red[0] + red[1] + red[2] + red[3]) * (1.f / D) + 1e-6f);
  const float4 wv = *(const float4*)(w + tid * 4);
  union { ushort4 u; bf16 b[4]; } o;
  o.b[0] = __float2bfloat16(v.x * inv * wv.x);
  o.b[1] = __float2bfloat16(v.y * inv * wv.y);
  o.b[2] = __float2bfloat16(v.z * inv * wv.z);
  o.b[3] = __float2bfloat16(v.w * inv * wv.w);
  *(ushort4*)((unsigned short*)out + row * D + tid * 4) = o.u;
}

// ---------------- routing ----------------
__global__ void route_init(int* counts, int* cursors, int* perm) {
  const int i = blockIdx.x * 256 + threadIdx.x;
  if (i < E) { counts[i] = 0; cursors[i] = 0; }
  if (i < SLOTS) perm[i] = -1;
}
__global__ void route_count(const int* __restrict__ mt, int* counts) {
  const int i = blockIdx.x * 256 + threadIdx.x;
  if (i < TOK) atomicAdd(&counts[mt[i]], 1);
}
__global__ void route_offsets(const int* __restrict__ counts, int* aoff) {
  if (threadIdx.x == 0) {
    int off = 0; aoff[0] = 0;
    for (int e = 0; e < E; ++e) { off += (counts[e] + 255) & ~255; aoff[e + 1] = off; }
  }
}
__global__ void route_scatter(const int* __restrict__ mt, const int* __restrict__ aoff,
                              int* cursors, int* perm) {
  const int i = blockIdx.x * 256 + threadIdx.x;
  if (i < TOK) { const int e = mt[i]; perm[aoff[e] + atomicAdd(&cursors[e], 1)] = i; }
}

// -------- QKV GEMM: 256x256 tile, 4-phase, latency-covered staging --------
// Phase order (ks,mih): (0,0)(1,0)(0,1)(1,1); B frags cached per-ks (bfr0/bfr1).
// Stage halves: 0=B-lo 1=B-hi 2=A-even(rows 0-63,128-191) 3=A-odd(64-127,192-255);
// each half issued >=2 phases before first use; vmcnt(4) keeps 2 halves in flight.
__global__ __launch_bounds__(512) void qkv8p(
    const bf16* __restrict__ A, const bf16* __restrict__ Bt,
    const float* __restrict__ c_t, const float* __restrict__ s_t,
    bf16* __restrict__ o_q, bf16* __restrict__ o_k, bf16* __restrict__ o_v) {
  constexpr int K = 1024, NT = K / 64;
  __shared__ __align__(16) bf16 LA[2][256 * 64];
  __shared__ __align__(16) bf16 LB[2][256 * 64];
  const int tid = threadIdx.x;
  const int lane = tid & 63, wv = tid >> 6;
  const int wm = wv >> 2, wn = wv & 3;
  const int rl = lane & 15, kg = lane >> 4;
  const int gx = gridDim.x;               // 12
  const int nwg = gx * gridDim.y;         // 384 (%8==0)
  int bid = blockIdx.y * gx + blockIdx.x;
  bid = (bid & 7) * (nwg >> 3) + (bid >> 3);
  const int nbase = (bid % gx) * 256, mbase = (bid / gx) * 256;
  f32x4 acc[8][4] = {};
  const int srow = tid >> 3;
  const int sc = (tid & 7) ^ ((srow >> 1) & 7);
  const bf16* Ag = A + (size_t)(mbase + srow) * K + sc * 8;
  const bf16* Bg = Bt + (size_t)(nbase + srow) * K + sc * 8;

  auto stage = [&](int t, int h) {
    const int buf = t & 1;
    if (h < 2) {
      const bf16* src = Bg + (size_t)(h * 128) * K + t * 64;
      bf16* dst = &LB[buf][0] + h * 128 * 64 + tid * 8;
      async16(src, dst);
      async16(src + (size_t)64 * K, dst + 64 * 64);
    } else {
      const int rh = h - 2;
      const bf16* src = Ag + (size_t)(rh * 64) * K + t * 64;
      bf16* dst = &LA[buf][0] + rh * 64 * 64 + tid * 8;
      async16(src, dst);
      async16(src + (size_t)128 * K, dst + 128 * 64);
    }
  };

  auto phaseC = [&](int t, int ks, int mih, bf16x8 (&bfr)[4], bool loadB) {
    const int buf = t & 1;
    const u32 ab = lds_off(&LA[buf][0]);
    const u32 bb = lds_off(&LB[buf][0]);
    bf16x8 af[4];
#pragma unroll
    for (int mi = 0; mi < 4; ++mi) {
      const int row = wm * 128 + mih * 64 + mi * 16 + rl;
      const u32 ph = (u32)((ks * 4 + kg) ^ ((row >> 1) & 7));
      af[mi] = dsr128(ab + (u32)row * 128 + ph * 16);
    }
    if (loadB) {
#pragma unroll
      for (int ni = 0; ni < 4; ++ni) {
        const int row = wn * 64 + ni * 16 + rl;
        const u32 ph = (u32)((ks * 4 + kg) ^ ((row >> 1) & 7));
        bfr[ni] = dsr128(bb + (u32)row * 128 + ph * 16);
      }
    }
    asm volatile("s_waitcnt lgkmcnt(0)" ::: "memory");
    __builtin_amdgcn_sched_barrier(0);
    __builtin_amdgcn_s_setprio(1);
#pragma unroll
    for (int mi = 0; mi < 4; ++mi)
#pragma unroll
      for (int ni = 0; ni < 4; ++ni)
        acc[mih * 4 + mi][ni] =
            __builtin_amdgcn_mfma_f32_16x16x32_bf16(af[mi], bfr[ni], acc[mih * 4 + mi][ni], 0, 0, 0);
    __builtin_amdgcn_s_setprio(0);
  };

  bf16x8 bfr0[4], bfr1[4];
  stage(0, 0); stage(0, 1); stage(0, 2); stage(0, 3);
  for (int t = 0; t < NT; ++t) {
    const bool more = (t + 1 < NT);
    // p0: needs B-lo,B-hi,A-even of t
    if (more) {
      stage(t + 1, 0);
      asm volatile("s_waitcnt vmcnt(4)" ::: "memory");
    } else {
      asm volatile("s_waitcnt vmcnt(2)" ::: "memory");
    }
    __builtin_amdgcn_s_barrier();
    __builtin_amdgcn_sched_barrier(0);
    phaseC(t, 0, 0, bfr0, true);
    __builtin_amdgcn_s_barrier();
    __builtin_amdgcn_sched_barrier(0);
    // p1
    if (more) stage(t + 1, 1);
    phaseC(t, 1, 0, bfr1, true);
    if (more) {
      asm volatile("s_waitcnt vmcnt(4)" ::: "memory");  // drain t's A-odd before p2
    } else {
      asm volatile("s_waitcnt vmcnt(0)" ::: "memory");
    }
    __builtin_amdgcn_s_barrier();
    __builtin_amdgcn_sched_barrier(0);
    // p2
    if (more) stage(t + 1, 2);
    phaseC(t, 0, 1, bfr0, false);
    __builtin_amdgcn_s_barrier();
    __builtin_amdgcn_sched_barrier(0);
    // p3
    if (more) stage(t + 1, 3);
    phaseC(t, 1, 1, bfr1, false);
    __builtin_amdgcn_s_barrier();
    __builtin_amdgcn_sched_barrier(0);
  }

  const int colbase = nbase + wn * 64;
  const int part = colbase >> 10;
  const int head = (colbase & 1023) >> 6;
  const float qs = (part == 0) ? 0.18033688011112042f : 1.f;  // fold 0.125*log2e into Q
#pragma unroll
  for (int ai = 0; ai < 8; ++ai) {
    const int rowoff = (ai >> 2) * 64 + (ai & 3) * 16;
#pragma unroll
    for (int r = 0; r < 4; ++r) {
      const int grow = mbase + wm * 128 + rowoff + kg * 4 + r;
      const int bb = grow >> 11, sp = grow & (S - 1);
      if (part == 2) {
#pragma unroll
        for (int ni = 0; ni < 4; ++ni) {
          const int d = ni * 16 + rl;
          o_v[((size_t)(bb * NH + head) * HD + d) * S + sp] = __float2bfloat16(acc[ai][ni][r]);
        }
      } else {
        bf16* dst = (part == 0) ? o_q : o_k;
        const size_t base = ((size_t)(bb * NH + head) * S + sp) * HD;
#pragma unroll
        for (int np = 0; np < 2; ++np) {
          const int i = np * 16 + rl;
          const float c = c_t[sp * 32 + i];
          const float sn = s_t[sp * 32 + i];
          const float lo = acc[ai][np][r];
          const float hi = acc[ai][np + 2][r];
          dst[base + i] = __float2bfloat16((lo * c - hi * sn) * qs);
          dst[base + i + 32] = __float2bfloat16((hi * c + lo * sn) * qs);
        }
      }
    }
  }
}

// -------- FFN GEMMs on the same schedule; lda decouples row stride from K-split --------
// EPI 2: act[slot] = gelu(xn2[perm[slot]] @ w1[e]^T), K=1024, z=1.
// EPI 3: atomicAdd(out[perm[slot]], partial), K=1024 per z-split (z=4 over K=4096);
//        out pre-initialized to h by the out-proj epilogue.
template <int EPI, int K>
__global__ __launch_bounds__(512) void ffn4p(
    const bf16* __restrict__ A, const bf16* __restrict__ Bt, int lda,
    const int* __restrict__ aoff, long long estride,
    bf16* __restrict__ o_act,
    const int* __restrict__ perm, float* __restrict__ o_out) {
  constexpr int NT = K / 64;
  __shared__ __align__(16) bf16 LA[2][256 * 64];
  __shared__ __align__(16) bf16 LB[2][256 * 64];
  const int tid = threadIdx.x;
  const int lane = tid & 63, wv = tid >> 6;
  const int wm = wv >> 2, wn = wv & 3;
  const int rl = lane & 15, kg = lane >> 4;
  const int gx = gridDim.x;
  const int nwg = gx * gridDim.y;  // 640 (FFN1) / 160 per z (FFN2), both %8==0
  int bid = blockIdx.y * gx + blockIdx.x;
  bid = (bid & 7) * (nwg >> 3) + (bid >> 3);
  const int nbase = (bid % gx) * 256, mbase = (bid / gx) * 256;
  if (mbase >= aoff[E]) return;  // beyond actual padded slot count (uniform exit, no barriers yet)
  const size_t koff = (size_t)blockIdx.z * K;
  int e = 0;
#pragma unroll
  for (int t = 0; t < E - 1; ++t) e += (mbase >= aoff[t + 1]) ? 1 : 0;
  const bf16* Btp = Bt + (size_t)e * estride;

  f32x4 acc[8][4] = {};
  const int srow = tid >> 3;
  const int sc = (tid & 7) ^ ((srow >> 1) & 7);
  const bf16* Agr[4];  // row pointers for LDS rows c*64+srow (gathered for EPI 2)
#pragma unroll
  for (int c = 0; c < 4; ++c) {
    int slot = mbase + c * 64 + srow;
    if constexpr (EPI == 2) { const int pt = perm[slot]; slot = (pt < 0) ? 0 : pt; }
    Agr[c] = A + (size_t)slot * lda + koff + sc * 8;
  }
  const bf16* Bg = Btp + (size_t)(nbase + srow) * lda + koff + sc * 8;

  auto stage = [&](int t, int h) {  // 0=B-lo 1=B-hi 2=A-even 3=A-odd
    const int buf = t & 1;
    if (h < 2) {
      const bf16* src = Bg + (size_t)(h * 128) * lda + t * 64;
      bf16* dst = &LB[buf][0] + h * 128 * 64 + tid * 8;
      async16(src, dst);
      async16(src + (size_t)64 * lda, dst + 64 * 64);
    } else {
      const int rh = h - 2;
      bf16* dst = &LA[buf][0] + rh * 64 * 64 + tid * 8;
      async16(Agr[rh] + t * 64, dst);
      async16(Agr[rh + 2] + t * 64, dst + 128 * 64);
    }
  };

  auto phaseC = [&](int t, int ks, int mih, bf16x8 (&bfr)[4], bool loadB) {
    const int buf = t & 1;
    const u32 ab = lds_off(&LA[buf][0]);
    const u32 bb = lds_off(&LB[buf][0]);
    bf16x8 af[4];
#pragma unroll
    for (int mi = 0; mi < 4; ++mi) {
      const int row = wm * 128 + mih * 64 + mi * 16 + rl;
      const u32 ph = (u32)((ks * 4 + kg) ^ ((row >> 1) & 7));
      af[mi] = dsr128(ab + (u32)row * 128 + ph * 16);
    }
    if (loadB) {
#pragma unroll
      for (int ni = 0; ni < 4; ++ni) {
        const int row = wn * 64 + ni * 16 + rl;
        const u32 ph = (u32)((ks * 4 + kg) ^ ((row >> 1) & 7));
        bfr[ni] = dsr128(bb + (u32)row * 128 + ph * 16);
      }
    }
    asm volatile("s_waitcnt lgkmcnt(0)" ::: "memory");
    __builtin_amdgcn_sched_barrier(0);
    __builtin_amdgcn_s_setprio(1);
#pragma unroll
    for (int mi = 0; mi < 4; ++mi)
#pragma unroll
      for (int ni = 0; ni < 4; ++ni)
        acc[mih * 4 + mi][ni] =
            __builtin_amdgcn_mfma_f32_16x16x32_bf16(af[mi], bfr[ni], acc[mih * 4 + mi][ni], 0, 0, 0);
    __builtin_amdgcn_s_setprio(0);
  };

  bf16x8 bfr0[4], bfr1[4];
  stage(0, 0); stage(0, 1); stage(0, 2); stage(0, 3);
  for (int t = 0; t < NT; ++t) {
    const bool more = (t + 1 < NT);
    if (more) {
      stage(t + 1, 0);
      asm volatile("s_waitcnt vmcnt(4)" ::: "memory");
    } else {
      asm volatile("s_waitcnt vmcnt(2)" ::: "memory");
    }
    __builtin_amdgcn_s_barrier();
    __builtin_amdgcn_sched_barrier(0);
    phaseC(t, 0, 0, bfr0, true);
    __builtin_amdgcn_s_barrier();
    __builtin_amdgcn_sched_barrier(0);
    if (more) stage(t + 1, 1);
    phaseC(t, 1, 0, bfr1, true);
    if (more) {
      asm volatile("s_waitcnt vmcnt(4)" ::: "memory");
    } else {
      asm volatile("s_waitcnt vmcnt(0)" ::: "memory");
    }
    __builtin_amdgcn_s_barrier();
    __builtin_amdgcn_sched_barrier(0);
    if (more) stage(t + 1, 2);
    phaseC(t, 0, 1, bfr0, false);
    __builtin_amdgcn_s_barrier();
    __builtin_amdgcn_sched_barrier(0);
    if (more) stage(t + 1, 3);
    phaseC(t, 1, 1, bfr1, false);
    __builtin_amdgcn_s_barrier();
    __builtin_amdgcn_sched_barrier(0);
  }

#pragma unroll
  for (int ai = 0; ai < 8; ++ai) {
    const int rowoff = (ai >> 2) * 64 + (ai & 3) * 16;
#pragma unroll
    for (int r = 0; r < 4; ++r) {
      const int grow = mbase + wm * 128 + rowoff + kg * 4 + r;
#pragma unroll
      for (int ni = 0; ni < 4; ++ni) {
        const int gcol = nbase + wn * 64 + ni * 16 + rl;
        const float vv = acc[ai][ni][r];
        if constexpr (EPI == 2) {
          o_act[(size_t)grow * 4096 + gcol] = __float2bfloat16(gelu_fast(vv));
        } else {
          const int tk = perm[grow];
          if (tk >= 0) atomicAdd(&o_out[(size_t)tk * 1024 + gcol], vv);
        }
      }
    }
  }
}

// ---------------- out-proj GEMM (2-phase 128^2). EPI 1: h = x + acc, dual-write out. ----
template <int EPI, int BM>
__global__ __launch_bounds__(2 * BM) void gemm_bt(
    const bf16* __restrict__ A, const bf16* __restrict__ Bt, int M, int N, int K,
    const float* __restrict__ xres, float* __restrict__ o_h, float* __restrict__ o_out) {
  constexpr int WN = BM / 64;
  constexpr int MR = BM / 2;
  constexpr int M_FR = MR / 16;
  __shared__ __align__(16) bf16 As[2][BM * 32];
  __shared__ __align__(16) bf16 Bs[2][BM * 32];
  const int tid = threadIdx.x;
  const int lane = tid & 63, wv = tid >> 6;
  const int wm = wv / WN, wn = wv % WN;
  const int rl = lane & 15, kg = lane >> 4;
  const int gx = gridDim.x;
  const int nwg = gx * gridDim.y;
  int bid = blockIdx.y * gx + blockIdx.x;
  bid = (bid & 7) * (nwg >> 3) + (bid >> 3);
  const int nbase = (bid % gx) * BM, mbase = (bid / gx) * BM;
  f32x4 acc[M_FR][4] = {};
  const int srow = tid >> 2;
  const int sc = (tid & 3) ^ ((srow >> 1) & 3);
  const bf16* Agp[2];
#pragma unroll
  for (int c = 0; c < 2; ++c) Agp[c] = A + (size_t)(mbase + c * MR + srow) * K + sc * 8;
  const bf16* Bg = Bt + (size_t)(nbase + srow) * K + sc * 8;

  auto stage = [&](int bi, int ko) {
#pragma unroll
    for (int c = 0; c < 2; ++c) {
      async16(Agp[c] + ko, &As[bi][c * MR * 32 + wv * 512]);
      async16(Bg + (size_t)(c * MR) * K + ko, &Bs[bi][c * MR * 32 + wv * 512]);
    }
  };
  auto compute = [&](int bi) {
    bf16x8 af[M_FR], bfr[4];
#pragma unroll
    for (int mi = 0; mi < M_FR; ++mi) {
      const int row = wm * MR + mi * 16 + rl;
      af[mi] = *(const bf16x8*)&As[bi][row * 32 + ((kg ^ ((row >> 1) & 3))) * 8];
    }
#pragma unroll
    for (int ni = 0; ni < 4; ++ni) {
      const int row = wn * 64 + ni * 16 + rl;
      bfr[ni] = *(const bf16x8*)&Bs[bi][row * 32 + ((kg ^ ((row >> 1) & 3))) * 8];
    }
#pragma unroll
    for (int mi = 0; mi < M_FR; ++mi)
#pragma unroll
      for (int ni = 0; ni < 4; ++ni)
        acc[mi][ni] = __builtin_amdgcn_mfma_f32_16x16x32_bf16(af[mi], bfr[ni], acc[mi][ni], 0, 0, 0);
  };

  const int nk = K >> 5;
  stage(0, 0);
  __syncthreads();
  for (int kb = 0; kb < nk; ++kb) {
    if (kb + 1 < nk) stage((kb + 1) & 1, (kb + 1) * 32);
    compute(kb & 1);
    __syncthreads();
  }

#pragma unroll
  for (int mi = 0; mi < M_FR; ++mi) {
#pragma unroll
    for (int ni = 0; ni < 4; ++ni) {
#pragma unroll
      for (int r = 0; r < 4; ++r) {
        const int grow = mbase + wm * MR + mi * 16 + kg * 4 + r;
        const int gcol = nbase + wn * 64 + ni * 16 + rl;
        const size_t ix = (size_t)grow * 1024 + gcol;
        const float v = xres[ix] + acc[mi][ni][r];
        o_h[ix] = v;
        o_out[ix] = v;  // FFN2 split-K accumulates on top of this
      }
    }
  }
}

// ------- flash attention, swapped-operand 32x32, KVBLK=64; Q pre-scaled by 0.125*log2e ----
__global__ __launch_bounds__(128, 4) void attn_kernel(const bf16* __restrict__ Qb,
                                                      const bf16* __restrict__ Kb,
                                                      const bf16* __restrict__ Vt,
                                                      bf16* __restrict__ AO) {
  const int bh = blockIdx.x;  // x fastest => XCD = bh % 8
  const int w = threadIdx.x >> 6, lane = threadIdx.x & 63;
  const int q = lane & 31, hi = lane >> 5;
  const bf16* Qp = Qb + (size_t)bh * S * HD;
  const bf16* Kp = Kb + (size_t)bh * S * HD;
  const bf16* Vp = Vt + (size_t)bh * S * HD;  // [HD][S]
  const int b = bh >> 4, h = bh & 15;
  __shared__ __align__(16) bf16 Pl[2][4][32][16];  // [wave][slice][q][k']
  const int qt = (S / 32 - 1) - (blockIdx.y * 2 + w);  // heaviest first
  const int qrow0 = qt * 32;
  bf16x8 qf[4];
#pragma unroll
  for (int t = 0; t < 4; ++t)
    qf[t] = *(const bf16x8*)(Qp + (size_t)(qrow0 + q) * HD + t * 16 + hi * 8);
  f32x16 oa0 = {}, oa1 = {};
  float m = -INFINITY, l = 0.f;
  const int nt = (qt + 2) >> 1;  // ceil((qt+1)/2) 64-wide tiles
  for (int kt = 0; kt < nt; ++kt) {
    const int kvb = kt * 64;
    f32x16 sa0 = {}, sa1 = {};
#pragma unroll
    for (int t = 0; t < 4; ++t) {
      const bf16x8 kf0 = *(const bf16x8*)(Kp + (size_t)(kvb + q) * HD + t * 16 + hi * 8);
      sa0 = __builtin_amdgcn_mfma_f32_32x32x16_bf16(kf0, qf[t], sa0, 0, 0, 0);
    }
#pragma unroll
    for (int t = 0; t < 4; ++t) {
      const bf16x8 kf1 = *(const bf16x8*)(Kp + (size_t)(kvb + 32 + q) * HD + t * 16 + hi * 8);
      sa1 = __builtin_amdgcn_mfma_f32_32x32x16_bf16(kf1, qf[t], sa1, 0, 0, 0);
    }
    if (kvb + 63 > qrow0) {  // only diagonal/edge tiles need masking
#pragma unroll
      for (int r = 0; r < 16; ++r) {
        const int kloc = (r & 3) + 8 * (r >> 2) + 4 * hi;
        sa0[r] = (kvb + kloc > qrow0 + q) ? -3.0e38f : sa0[r];
        sa1[r] = (kvb + 32 + kloc > qrow0 + q) ? -3.0e38f : sa1[r];
      }
    }
    float vm;
    {
      float a0 = fmaxf(fmaxf(sa0[0], sa0[1]), fmaxf(sa0[2], sa0[3]));
      float a1 = fmaxf(fmaxf(sa0[4], sa0[5]), fmaxf(sa0[6], sa0[7]));
      float a2 = fmaxf(fmaxf(sa0[8], sa0[9]), fmaxf(sa0[10], sa0[11]));
      float a3 = fmaxf(fmaxf(sa0[12], sa0[13]), fmaxf(sa0[14], sa0[15]));
      float b0 = fmaxf(fmaxf(sa1[0], sa1[1]), fmaxf(sa1[2], sa1[3]));
      float b1 = fmaxf(fmaxf(sa1[4], sa1[5]), fmaxf(sa1[6], sa1[7]));
      float b2 = fmaxf(fmaxf(sa1[8], sa1[9]), fmaxf(sa1[10], sa1[11]));
      float b3 = fmaxf(fmaxf(sa1[12], sa1[13]), fmaxf(sa1[14], sa1[15]));
      vm = fmaxf(fmaxf(fmaxf(a0, a1), fmaxf(a2, a3)), fmaxf(fmaxf(b0, b1), fmaxf(b2, b3)));
    }
    vm = fmaxf(vm, __shfl_xor(vm, 32));
    const bool grow = __any(vm > m);  // T13 (exact)
    const float mn = grow ? fmaxf(m, vm) : m;
#pragma unroll
    for (int r = 0; r < 16; ++r) {
      sa0[r] = exp2f(sa0[r] - mn);
      sa1[r] = exp2f(sa1[r] - mn);
    }
    float ps;
    {
      float a0 = (sa0[0] + sa0[1]) + (sa0[2] + sa0[3]);
      float a1 = (sa0[4] + sa0[5]) + (sa0[6] + sa0[7]);
      float a2 = (sa0[8] + sa0[9]) + (sa0[10] + sa0[11]);
      float a3 = (sa0[12] + sa0[13]) + (sa0[14] + sa0[15]);
      float b0 = (sa1[0] + sa1[1]) + (sa1[2] + sa1[3]);
      float b1 = (sa1[4] + sa1[5]) + (sa1[6] + sa1[7]);
      float b2 = (sa1[8] + sa1[9]) + (sa1[10] + sa1[11]);
      float b3 = (sa1[12] + sa1[13]) + (sa1[14] + sa1[15]);
      ps = ((a0 + a1) + (a2 + a3)) + ((b0 + b1) + (b2 + b3));
    }
    ps += __shfl_xor(ps, 32);
    if (grow) {
      const float scs = exp2f(m - mn);
      l = l * scs + ps;
      m = mn;
#pragma unroll
      for (int r = 0; r < 16; ++r) { oa0[r] *= scs; oa1[r] *= scs; }
    } else {
      l += ps;
    }
#pragma unroll
    for (int g = 0; g < 8; ++g) {
      union { ushort4 u4; bf16 bb[4]; } pk;
#pragma unroll
      for (int j = 0; j < 4; ++j) {
        const int r = 4 * (g & 3) + j;
        pk.bb[j] = __float2bfloat16((g < 4) ? sa0[r] : sa1[r]);
      }
      *(ushort4*)&Pl[w][g >> 1][q][8 * (g & 1) + 4 * hi] = pk.u4;
    }
#pragma unroll
    for (int s2i = 0; s2i < 4; ++s2i) {
      const bf16x8 pf = *(const bf16x8*)&Pl[w][s2i][q][8 * hi];
      const bf16x8 vf0 = *(const bf16x8*)(Vp + (size_t)q * S + kvb + 16 * s2i + 8 * hi);
      const bf16x8 vf1 = *(const bf16x8*)(Vp + (size_t)(32 + q) * S + kvb + 16 * s2i + 8 * hi);
      oa0 = __builtin_amdgcn_mfma_f32_32x32x16_bf16(vf0, pf, oa0, 0, 0, 0);
      oa1 = __builtin_amdgcn_mfma_f32_32x32x16_bf16(vf1, pf, oa1, 0, 0, 0);
    }
  }
  const float invl = 1.f / l;
#pragma unroll
  for (int n = 0; n < 2; ++n) {
#pragma unroll
    for (int g = 0; g < 4; ++g) {
      union { ushort4 u4; bf16 bb[4]; } o4;
#pragma unroll
      for (int mi = 0; mi < 4; ++mi) {
        const float val = (n ? oa1[4 * g + mi] : oa0[4 * g + mi]) * invl;
        o4.bb[mi] = __float2bfloat16(val);
      }
      const int d = n * 32 + 8 * g + 4 * hi;
      *(ushort4*)&AO[((size_t)(b * S + qrow0 + q)) * D + h * HD + d] = o4.u4;
    }
  }
}

// ---------------- host launch ----------------
extern "C" void kernel_launch(void* const* d_in, const int* in_sizes, int n_in,
                              void* d_out, int out_size, void* d_ws, size_t ws_size,
                              hipStream_t stream) {
  const float* x = (const float*)d_in[0];
  const int* mt = (const int*)d_in[1];
  const float* rms1 = (const float*)d_in[2];
  const float* wqkv = (const float*)d_in[3];
  const float* wo = (const float*)d_in[4];
  const float* rms2 = (const float*)d_in[5];
  const float* w1 = (const float*)d_in[6];
  const float* w2 = (const float*)d_in[7];
  float* out = (float*)d_out;
  (void)in_sizes; (void)n_in; (void)out_size; (void)ws_size;

  char* ws = (char*)d_ws;
  size_t off = 0;
  auto alloc = [&](size_t b) { void* p = ws + off; off = (off + b + 255) & ~(size_t)255; return p; };
  bf16* wqkvT = (bf16*)alloc((size_t)3072 * 1024 * 2);
  bf16* woT   = (bf16*)alloc((size_t)1024 * 1024 * 2);
  bf16* w1T   = (bf16*)alloc((size_t)E * F * D * 2);
  bf16* w2T   = (bf16*)alloc((size_t)E * D * F * 2);
  float* cosT = (float*)alloc((size_t)S * 32 * 4);
  float* sinT = (float*)alloc((size_t)S * 32 * 4);
  float* hbuf = (float*)alloc((size_t)TOK * D * 4);
  bf16* xn2   = (bf16*)alloc((size_t)TOK * D * 2);  // MoE rmsnorm out (separate from R)
  int* counts  = (int*)alloc(E * 4);
  int* cursors = (int*)alloc(E * 4);
  int* aoff    = (int*)alloc((E + 1) * 4);
  int* perm    = (int*)alloc(SLOTS * 4);
  char* R = (char*)alloc((size_t)5 * TOK * D * 2);  // xn|q|k|vT|ao, later reused as act
  bf16* xn = (bf16*)R;
  bf16* qb = (bf16*)(R + (size_t)1 * TOK * D * 2);
  bf16* kb = (bf16*)(R + (size_t)2 * TOK * D * 2);
  bf16* vb = (bf16*)(R + (size_t)3 * TOK * D * 2);  // Vt [bh][d][s]
  bf16* ao = (bf16*)(R + (size_t)4 * TOK * D * 2);
  bf16* act = (bf16*)R;  // SLOTS*F*2 = 83,886,080 B == 5*TOK*D*2; all of R dead by FFN1

  cvt_transpose<<<dim3(3072 / 64, 1024 / 64, 1), 256, 0, stream>>>(wqkv, wqkvT, 1024, 3072);
  cvt_transpose<<<dim3(1024 / 64, 1024 / 64, 1), 256, 0, stream>>>(wo, woT, 1024, 1024);
  cvt_transpose<<<dim3(4096 / 64, 1024 / 64, E), 256, 0, stream>>>(w1, w1T, 1024, 4096);
  cvt_transpose<<<dim3(1024 / 64, 4096 / 64, E), 256, 0, stream>>>(w2, w2T, 4096, 1024);
  rope_tables<<<dim3(S / 2), 64, 0, stream>>>(cosT, sinT);
  route_init<<<dim3((SLOTS + 255) / 256), 256, 0, stream>>>(counts, cursors, perm);
  route_count<<<dim3(TOK / 256), 256, 0, stream>>>(mt, counts);
  route_offsets<<<dim3(1), 64, 0, stream>>>(counts, aoff);
  route_scatter<<<dim3(TOK / 256), 256, 0, stream>>>(mt, aoff, cursors, perm);
  // attention path
  rmsnorm_k<<<dim3(TOK), 256, 0, stream>>>(x, rms1, xn);
  qkv8p<<<dim3(3072 / 256, TOK / 256), 512, 0, stream>>>(
      xn, wqkvT, cosT, sinT, qb, kb, vb);
  attn_kernel<<<dim3(64, S / 64), 128, 0, stream>>>(qb, kb, vb, ao);
  gemm_bt<1, 128><<<dim3(1024 / 128, TOK / 128), 256, 0, stream>>>(  // out-proj, dual-write
      ao, woT, TOK, 1024, 1024, x, hbuf, out);
  // MoE path
  rmsnorm_k<<<dim3(TOK), 256, 0, stream>>>(hbuf, rms2, xn2);
  ffn4p<2, 1024><<<dim3(4096 / 256, SLOTS / 256, 1), 512, 0, stream>>>(  // FFN1 + gather + gelu
      xn2, w1T, 1024, aoff, (long long)F * D, act, perm, nullptr);
  ffn4p<3, 1024><<<dim3(1024 / 256, SLOTS / 256, 4), 512, 0, stream>>>(  // FFN2 split-K=4 + scatter
      act, w2T, 4096, aoff, (long long)D * F, nullptr, perm, out);
}

// Round 3
// 698.613 us; speedup vs baseline: 1.0548x; 1.0548x over previous
//
#include <hip/hip_runtime.h>
#include <hip/hip_bf16.h>
#include <stdint.h>

typedef __hip_bfloat16 bf16;
typedef __attribute__((ext_vector_type(8))) short bf16x8;
typedef __attribute__((ext_vector_type(4))) float f32x4;
typedef __attribute__((ext_vector_type(16))) float f32x16;
typedef unsigned int u32;

static constexpr int Bsz = 4, S = 2048, D = 1024, E = 8, F = 4096, NH = 16, HD = 64;
static constexpr int TOK = Bsz * S;          // 8192 tokens
static constexpr int SLOTS = TOK + E * 128;  // 9216 padded routing slots (128-aligned experts)

#define DEV __device__ __forceinline__

DEV void async16(const bf16* g, bf16* l) {
  __builtin_amdgcn_global_load_lds((const __attribute__((address_space(1))) u32*)g,
                                   (__attribute__((address_space(3))) u32*)l, 16, 0, 0);
}

DEV u32 lds_off(const bf16* p) {
  return (u32)(uintptr_t)(__attribute__((address_space(3))) bf16*)p;
}

DEV bf16x8 dsr128(u32 addr) {  // asm ds_read: invisible to LDS alias analysis
  bf16x8 d;
  asm volatile("ds_read_b128 %0, %1" : "=v"(d) : "v"(addr));
  return d;
}

// gelu(x) = 0.5x(1+tanh(z)) = x * sigmoid(2z)
DEV float gelu_fast(float x) {
  const float z = 0.7978845608028654f * (x + 0.044715f * x * x * x);
  return x / (1.f + __expf(-2.f * z));
}

DEV u32 cvtpk(float lo, float hi) {  // word = (bf16(lo), bf16(hi)) packed
  u32 r;
  asm("v_cvt_pk_bf16_f32 %0, %1, %2" : "=v"(r) : "v"(lo), "v"(hi));
  return r;
}

// ---------------- small kernels ----------------

// fp32 [R][C] -> bf16 [C][R], 64x64 tiles: 16B/lane coalesced on BOTH sides
__global__ void cvt_transpose(const float* __restrict__ in, bf16* __restrict__ out, int R, int C) {
  __shared__ float t[64][65];
  const size_t zoff = (size_t)blockIdx.z * R * C;
  const int c0 = blockIdx.x * 64, r0 = blockIdx.y * 64;
  const int tid = threadIdx.x;
  const int lrow = tid >> 4, lcol = (tid & 15) * 4;
#pragma unroll
  for (int p = 0; p < 4; ++p) {
    const int r = lrow + p * 16;
    const float4 v = *(const float4*)(in + zoff + (size_t)(r0 + r) * C + c0 + lcol);
    t[r][lcol] = v.x; t[r][lcol + 1] = v.y; t[r][lcol + 2] = v.z; t[r][lcol + 3] = v.w;
  }
  __syncthreads();
  const int ow = tid >> 3, je = (tid & 7) * 8;
#pragma unroll
  for (int p = 0; p < 2; ++p) {
    const int oc = ow + p * 32;
    union { bf16x8 v; bf16 b[8]; } o8;
#pragma unroll
    for (int j = 0; j < 8; ++j) o8.b[j] = __float2bfloat16(t[je + j][oc]);
    *(bf16x8*)(out + zoff + (size_t)(c0 + oc) * R + r0 + je) = o8.v;
  }
}

__global__ void rope_tables(float* __restrict__ cosT, float* __restrict__ sinT) {
  const int s = blockIdx.x * 2 + (threadIdx.x >> 5);
  const int i = threadIdx.x & 31;
  const float inv_freq = powf(10000.f, -(float)i / 32.f);
  const float ang = (float)s * inv_freq;
  cosT[s * 32 + i] = cosf(ang);
  sinT[s * 32 + i] = sinf(ang);
}

__global__ void rmsnorm_k(const float* __restrict__ x, const float* __restrict__ w, bf16* __restrict__ out) {
  const size_t row = blockIdx.x;
  const int tid = threadIdx.x;
  const float4 v = *(const float4*)(x + row * D + tid * 4);
  float ss = v.x * v.x + v.y * v.y + v.z * v.z + v.w * v.w;
#pragma unroll
  for (int off = 1; off < 64; off <<= 1) ss += __shfl_xor(ss, off);
  __shared__ float red[4];
  if ((tid & 63) == 0) red[tid >> 6] = ss;
  __syncthreads();
  const float inv = rsqrtf((red[0] + red[1] + red[2] + red[3]) * (1.f / D) + 1e-6f);
  const float4 wv = *(const float4*)(w + tid * 4);
  union { ushort4 u; bf16 b[4]; } o;
  o.b[0] = __float2bfloat16(v.x * inv * wv.x);
  o.b[1] = __float2bfloat16(v.y * inv * wv.y);
  o.b[2] = __float2bfloat16(v.z * inv * wv.z);
  o.b[3] = __float2bfloat16(v.w * inv * wv.w);
  *(ushort4*)((unsigned short*)out + row * D + tid * 4) = o.u;
}

// ---------------- routing ----------------
__global__ void route_init(int* counts, int* cursors, int* perm) {
  const int i = blockIdx.x * 256 + threadIdx.x;
  if (i < E) { counts[i] = 0; cursors[i] = 0; }
  if (i < SLOTS) perm[i] = -1;
}
__global__ void route_count(const int* __restrict__ mt, int* counts) {
  const int i = blockIdx.x * 256 + threadIdx.x;
  if (i < TOK) atomicAdd(&counts[mt[i]], 1);
}
__global__ void route_offsets(const int* __restrict__ counts, int* aoff) {
  if (threadIdx.x == 0) {
    int off = 0; aoff[0] = 0;
    for (int e = 0; e < E; ++e) { off += (counts[e] + 127) & ~127; aoff[e + 1] = off; }
  }
}
__global__ void route_scatter(const int* __restrict__ mt, const int* __restrict__ aoff,
                              int* cursors, int* perm) {
  const int i = blockIdx.x * 256 + threadIdx.x;
  if (i < TOK) { const int e = mt[i]; perm[aoff[e] + atomicAdd(&cursors[e], 1)] = i; }
}

// -------- QKV GEMM: 4-phase/tile counted-vmcnt pipeline (r13-proven, verbatim) --------
__global__ __launch_bounds__(512) void qkv8p(
    const bf16* __restrict__ A, const bf16* __restrict__ Bt,
    const float* __restrict__ c_t, const float* __restrict__ s_t,
    bf16* __restrict__ o_q, bf16* __restrict__ o_k, bf16* __restrict__ o_v) {
  constexpr int K = 1024, NT = K / 64;
  __shared__ __align__(16) bf16 LA[2][256 * 64];
  __shared__ __align__(16) bf16 LB[2][256 * 64];
  const int tid = threadIdx.x;
  const int lane = tid & 63, wv = tid >> 6;
  const int wm = wv >> 2, wn = wv & 3;
  const int rl = lane & 15, kg = lane >> 4;
  const int gx = gridDim.x;               // 12
  const int nwg = gx * gridDim.y;         // 384 (%8==0)
  int bid = blockIdx.y * gx + blockIdx.x;
  bid = (bid & 7) * (nwg >> 3) + (bid >> 3);
  const int nbase = (bid % gx) * 256, mbase = (bid / gx) * 256;
  f32x4 acc[8][4] = {};
  const int srow = tid >> 3;
  const int sc = (tid & 7) ^ ((srow >> 1) & 7);
  const bf16* Ag = A + (size_t)(mbase + srow) * K + sc * 8;
  const bf16* Bg = Bt + (size_t)(nbase + srow) * K + sc * 8;

  auto stage = [&](int t, int h) {  // h: 0=A-lo 1=A-hi 2=B-lo 3=B-hi
    const int buf = t & 1;
    const int mat = h >> 1, rh = h & 1;
    const bf16* src = (mat ? Bg : Ag) + (size_t)(rh * 128) * K + t * 64;
    bf16* dst = (mat ? &LB[buf][0] : &LA[buf][0]) + rh * 128 * 64 + tid * 8;
    async16(src, dst);
    async16(src + (size_t)64 * K, dst + 64 * 64);
  };

  bf16x8 bfr[4];
  auto phaseC = [&](int t, int ks, int mih, bool loadB) {
    const int buf = t & 1;
    const u32 ab = lds_off(&LA[buf][0]);
    const u32 bb = lds_off(&LB[buf][0]);
    bf16x8 af[4];
#pragma unroll
    for (int mi = 0; mi < 4; ++mi) {
      const int row = wm * 128 + mih * 64 + mi * 16 + rl;
      const u32 ph = (u32)((ks * 4 + kg) ^ ((row >> 1) & 7));
      af[mi] = dsr128(ab + (u32)row * 128 + ph * 16);
    }
    if (loadB) {
#pragma unroll
      for (int ni = 0; ni < 4; ++ni) {
        const int row = wn * 64 + ni * 16 + rl;
        const u32 ph = (u32)((ks * 4 + kg) ^ ((row >> 1) & 7));
        bfr[ni] = dsr128(bb + (u32)row * 128 + ph * 16);
      }
    }
    asm volatile("s_waitcnt lgkmcnt(0)" ::: "memory");
    __builtin_amdgcn_sched_barrier(0);
    __builtin_amdgcn_s_setprio(1);
#pragma unroll
    for (int mi = 0; mi < 4; ++mi)
#pragma unroll
      for (int ni = 0; ni < 4; ++ni)
        acc[mih * 4 + mi][ni] =
            __builtin_amdgcn_mfma_f32_16x16x32_bf16(af[mi], bfr[ni], acc[mih * 4 + mi][ni], 0, 0, 0);
    __builtin_amdgcn_s_setprio(0);
  };

  stage(0, 0); stage(0, 1); stage(0, 2); stage(0, 3);
  for (int t = 0; t < NT; ++t) {
    const bool more = (t + 1 < NT);
#pragma unroll
    for (int p = 0; p < 4; ++p) {
      if (p == 0) {
        if (more) {
          stage(t + 1, 0);
          asm volatile("s_waitcnt vmcnt(2)" ::: "memory");
        } else {
          asm volatile("s_waitcnt vmcnt(0)" ::: "memory");
        }
        __builtin_amdgcn_s_barrier();
        __builtin_amdgcn_sched_barrier(0);
      } else if (more) {
        stage(t + 1, p);
      }
      phaseC(t, p >> 1, p & 1, (p & 1) == 0);
      __builtin_amdgcn_s_barrier();
      __builtin_amdgcn_sched_barrier(0);
    }
  }

  const int colbase = nbase + wn * 64;
  const int part = colbase >> 10;
  const int head = (colbase & 1023) >> 6;
  const float qs = (part == 0) ? 0.18033688011112042f : 1.f;  // fold 0.125*log2e into Q
#pragma unroll
  for (int ai = 0; ai < 8; ++ai) {
    const int rowoff = (ai >> 2) * 64 + (ai & 3) * 16;
#pragma unroll
    for (int r = 0; r < 4; ++r) {
      const int grow = mbase + wm * 128 + rowoff + kg * 4 + r;
      const int bb = grow >> 11, sp = grow & (S - 1);
      if (part == 2) {
#pragma unroll
        for (int ni = 0; ni < 4; ++ni) {
          const int d = ni * 16 + rl;
          o_v[((size_t)(bb * NH + head) * HD + d) * S + sp] = __float2bfloat16(acc[ai][ni][r]);
        }
      } else {
        bf16* dst = (part == 0) ? o_q : o_k;
        const size_t base = ((size_t)(bb * NH + head) * S + sp) * HD;
#pragma unroll
        for (int np = 0; np < 2; ++np) {
          const int i = np * 16 + rl;
          const float c = c_t[sp * 32 + i];
          const float sn = s_t[sp * 32 + i];
          const float lo = acc[ai][np][r];
          const float hi = acc[ai][np + 2][r];
          dst[base + i] = __float2bfloat16((lo * c - hi * sn) * qs);
          dst[base + i + 32] = __float2bfloat16((hi * c + lo * sn) * qs);
        }
      }
    }
  }
}

// ---------------- GEMM: C = A[M,K] * Bt[N,K]^T (r11/r14/r16-proven 2-phase) ----------------
// EPI 1: h = x + acc.  EPI 2: FFN1 + fused gather, act=gelu.  EPI 3: out[perm] = h + acc.
template <int EPI, int BM>
__global__ __launch_bounds__(2 * BM) void gemm_bt(
    const bf16* __restrict__ A, const bf16* __restrict__ Bt, int M, int N, int K,
    const int* __restrict__ aoff, long long estride,
    const float* __restrict__ xres, float* __restrict__ o_h,
    bf16* __restrict__ o_act,
    const int* __restrict__ perm, const float* __restrict__ hres, float* __restrict__ o_out) {
  constexpr int WN = BM / 64;
  constexpr int MR = BM / 2;
  constexpr int M_FR = MR / 16;
  __shared__ __align__(16) bf16 As[2][BM * 32];
  __shared__ __align__(16) bf16 Bs[2][BM * 32];
  const int tid = threadIdx.x;
  const int lane = tid & 63, wv = tid >> 6;
  const int wm = wv / WN, wn = wv % WN;
  const int rl = lane & 15, kg = lane >> 4;
  const int gx = gridDim.x;
  const int nwg = gx * gridDim.y;
  int bid = blockIdx.y * gx + blockIdx.x;
  bid = (bid & 7) * (nwg >> 3) + (bid >> 3);
  const int nbase = (bid % gx) * BM, mbase = (bid / gx) * BM;
  const bf16* Btp = Bt;
  if constexpr (EPI >= 2) {
    int e = 0;
#pragma unroll
    for (int t = 0; t < E - 1; ++t) e += (mbase >= aoff[t + 1]) ? 1 : 0;
    Btp = Bt + (size_t)e * estride;
  }
  f32x4 acc[M_FR][4] = {};
  const int srow = tid >> 2;
  const int sc = (tid & 3) ^ ((srow >> 1) & 3);
  const bf16* Agp[2];
#pragma unroll
  for (int c = 0; c < 2; ++c) {
    int rowslot = mbase + c * MR + srow;
    if constexpr (EPI == 2) {
      const int t = perm[rowslot];
      rowslot = (t < 0) ? 0 : t;
    }
    Agp[c] = A + (size_t)rowslot * K + sc * 8;
  }
  const bf16* Bg = Btp + (size_t)(nbase + srow) * K + sc * 8;

  auto stage = [&](int bi, int ko) {
#pragma unroll
    for (int c = 0; c < 2; ++c) {
      async16(Agp[c] + ko, &As[bi][c * MR * 32 + wv * 512]);
      async16(Bg + (size_t)(c * MR) * K + ko, &Bs[bi][c * MR * 32 + wv * 512]);
    }
  };
  auto compute = [&](int bi) {
    bf16x8 af[M_FR], bfr[4];
#pragma unroll
    for (int mi = 0; mi < M_FR; ++mi) {
      const int row = wm * MR + mi * 16 + rl;
      af[mi] = *(const bf16x8*)&As[bi][row * 32 + ((kg ^ ((row >> 1) & 3))) * 8];
    }
#pragma unroll
    for (int ni = 0; ni < 4; ++ni) {
      const int row = wn * 64 + ni * 16 + rl;
      bfr[ni] = *(const bf16x8*)&Bs[bi][row * 32 + ((kg ^ ((row >> 1) & 3))) * 8];
    }
#pragma unroll
    for (int mi = 0; mi < M_FR; ++mi)
#pragma unroll
      for (int ni = 0; ni < 4; ++ni)
        acc[mi][ni] = __builtin_amdgcn_mfma_f32_16x16x32_bf16(af[mi], bfr[ni], acc[mi][ni], 0, 0, 0);
  };

  const int nk = K >> 5;
  stage(0, 0);
  __syncthreads();
  for (int kb = 0; kb < nk; ++kb) {
    if (kb + 1 < nk) stage((kb + 1) & 1, (kb + 1) * 32);
    compute(kb & 1);
    __syncthreads();
  }

#pragma unroll
  for (int mi = 0; mi < M_FR; ++mi) {
#pragma unroll
    for (int ni = 0; ni < 4; ++ni) {
#pragma unroll
      for (int r = 0; r < 4; ++r) {
        const int grow = mbase + wm * MR + mi * 16 + kg * 4 + r;
        const int gcol = nbase + wn * 64 + ni * 16 + rl;
        const float vv = acc[mi][ni][r];
        if constexpr (EPI == 1) {
          const size_t ix = (size_t)grow * 1024 + gcol;
          o_h[ix] = xres[ix] + vv;
        } else if constexpr (EPI == 2) {
          o_act[(size_t)grow * 4096 + gcol] = __float2bfloat16(gelu_fast(vv));
        } else {
          const int t = perm[grow];
          if (t >= 0) {
            const size_t ix = (size_t)t * 1024 + gcol;
            o_out[ix] = hres[ix] + vv;
          }
        }
      }
    }
  }
}

// ------- flash attention, swapped-operand 32x32, KVBLK=64 -------
// Q pre-scaled by 0.125*log2e. No LDS: P transposed in-register via cvt_pk + permlane32_swap.
// K software-prefetched into same regs after last use; V issued early (before K prefetch) so
// the compiler's counted vmcnt for V leaves the K prefetch in flight.
__global__ __launch_bounds__(128, 3) void attn_kernel(const bf16* __restrict__ Qb,
                                                      const bf16* __restrict__ Kb,
                                                      const bf16* __restrict__ Vt,
                                                      bf16* __restrict__ AO) {
  const int bh = blockIdx.x;  // x fastest => XCD = bh % 8
  const int w = threadIdx.x >> 6, lane = threadIdx.x & 63;
  const int q = lane & 31, hi = lane >> 5;
  const bf16* Qp = Qb + (size_t)bh * S * HD;
  const bf16* Kp = Kb + (size_t)bh * S * HD;
  const bf16* Vp = Vt + (size_t)bh * S * HD;  // [HD][S]
  const int b = bh >> 4, h = bh & 15;
  const int qt = (S / 32 - 1) - (blockIdx.y * 2 + w);  // heaviest first
  const int qrow0 = qt * 32;
  bf16x8 qf[4];
#pragma unroll
  for (int t = 0; t < 4; ++t)
    qf[t] = *(const bf16x8*)(Qp + (size_t)(qrow0 + q) * HD + t * 16 + hi * 8);
  f32x16 oa0 = {}, oa1 = {};
  float m = -INFINITY, l = 0.f;
  const int nt = (qt + 2) >> 1;  // ceil((qt+1)/2) 64-wide tiles

  bf16x8 kf[8];
  auto loadK = [&](int kvb) {
#pragma unroll
    for (int t = 0; t < 4; ++t) {
      kf[t]     = *(const bf16x8*)(Kp + (size_t)(kvb + q) * HD + t * 16 + hi * 8);
      kf[4 + t] = *(const bf16x8*)(Kp + (size_t)(kvb + 32 + q) * HD + t * 16 + hi * 8);
    }
  };
  // pf(lane q,hi) element j = P[k = 16*s2i + 8*hi + j][q]; source sa[r]: k=(r&3)+8*(r>>2)+4*hi.
  // Quad-pack + permlane32_swap (A.hi <-> B.lo) redistributes the 4*hi offset across lane halves.
  auto packP = [&](float s0, float s1, float s2, float s3,
                   float s4, float s5, float s6, float s7) -> bf16x8 {
    u32 x0 = cvtpk(s0, s1), x1 = cvtpk(s2, s3);
    u32 y0 = cvtpk(s4, s5), y1 = cvtpk(s6, s7);
    asm volatile("v_permlane32_swap_b32 %0, %1" : "+v"(x0), "+v"(y0));
    asm volatile("v_permlane32_swap_b32 %0, %1" : "+v"(x1), "+v"(y1));
    union { u32 w[4]; bf16x8 v; } u;
    u.w[0] = x0; u.w[1] = x1; u.w[2] = y0; u.w[3] = y1;
    return u.v;
  };

  loadK(0);
  for (int kt = 0; kt < nt; ++kt) {
    const int kvb = kt * 64;
    f32x16 sa0 = {}, sa1 = {};
#pragma unroll
    for (int t = 0; t < 4; ++t) sa0 = __builtin_amdgcn_mfma_f32_32x32x16_bf16(kf[t], qf[t], sa0, 0, 0, 0);
#pragma unroll
    for (int t = 0; t < 4; ++t) sa1 = __builtin_amdgcn_mfma_f32_32x32x16_bf16(kf[4 + t], qf[t], sa1, 0, 0, 0);
    // early-issue V (consumed at PV, covered by softmax)
    bf16x8 vf0[4], vf1[4];
#pragma unroll
    for (int s2i = 0; s2i < 4; ++s2i) {
      vf0[s2i] = *(const bf16x8*)(Vp + (size_t)q * S + kvb + 16 * s2i + 8 * hi);
      vf1[s2i] = *(const bf16x8*)(Vp + (size_t)(32 + q) * S + kvb + 16 * s2i + 8 * hi);
    }
    // prefetch next K (issued after V; consumed next iteration)
    if (kt + 1 < nt) loadK(kvb + 64);
    if (kvb + 63 > qrow0) {  // only diagonal/edge tiles need masking
#pragma unroll
      for (int r = 0; r < 16; ++r) {
        const int kloc = (r & 3) + 8 * (r >> 2) + 4 * hi;
        sa0[r] = (kvb + kloc > qrow0 + q) ? -3.0e38f : sa0[r];
        sa1[r] = (kvb + 32 + kloc > qrow0 + q) ? -3.0e38f : sa1[r];
      }
    }
    float vm;
    {
      float a0 = fmaxf(fmaxf(sa0[0], sa0[1]), fmaxf(sa0[2], sa0[3]));
      float a1 = fmaxf(fmaxf(sa0[4], sa0[5]), fmaxf(sa0[6], sa0[7]));
      float a2 = fmaxf(fmaxf(sa0[8], sa0[9]), fmaxf(sa0[10], sa0[11]));
      float a3 = fmaxf(fmaxf(sa0[12], sa0[13]), fmaxf(sa0[14], sa0[15]));
      float b0 = fmaxf(fmaxf(sa1[0], sa1[1]), fmaxf(sa1[2], sa1[3]));
      float b1 = fmaxf(fmaxf(sa1[4], sa1[5]), fmaxf(sa1[6], sa1[7]));
      float b2 = fmaxf(fmaxf(sa1[8], sa1[9]), fmaxf(sa1[10], sa1[11]));
      float b3 = fmaxf(fmaxf(sa1[12], sa1[13]), fmaxf(sa1[14], sa1[15]));
      vm = fmaxf(fmaxf(fmaxf(a0, a1), fmaxf(a2, a3)), fmaxf(fmaxf(b0, b1), fmaxf(b2, b3)));
    }
    vm = fmaxf(vm, __shfl_xor(vm, 32));
    const bool grow = __any(vm > m);  // T13 (exact)
    const float mn = grow ? fmaxf(m, vm) : m;
#pragma unroll
    for (int r = 0; r < 16; ++r) {
      sa0[r] = exp2f(sa0[r] - mn);
      sa1[r] = exp2f(sa1[r] - mn);
    }
    float ps;
    {
      float a0 = (sa0[0] + sa0[1]) + (sa0[2] + sa0[3]);
      float a1 = (sa0[4] + sa0[5]) + (sa0[6] + sa0[7]);
      float a2 = (sa0[8] + sa0[9]) + (sa0[10] + sa0[11]);
      float a3 = (sa0[12] + sa0[13]) + (sa0[14] + sa0[15]);
      float b0 = (sa1[0] + sa1[1]) + (sa1[2] + sa1[3]);
      float b1 = (sa1[4] + sa1[5]) + (sa1[6] + sa1[7]);
      float b2 = (sa1[8] + sa1[9]) + (sa1[10] + sa1[11]);
      float b3 = (sa1[12] + sa1[13]) + (sa1[14] + sa1[15]);
      ps = ((a0 + a1) + (a2 + a3)) + ((b0 + b1) + (b2 + b3));
    }
    ps += __shfl_xor(ps, 32);
    if (grow) {
      const float scs = exp2f(m - mn);
      l = l * scs + ps;
      m = mn;
#pragma unroll
      for (int r = 0; r < 16; ++r) { oa0[r] *= scs; oa1[r] *= scs; }
    } else {
      l += ps;
    }
    {
      const bf16x8 pf0 = packP(sa0[0], sa0[1], sa0[2], sa0[3], sa0[4], sa0[5], sa0[6], sa0[7]);
      oa0 = __builtin_amdgcn_mfma_f32_32x32x16_bf16(vf0[0], pf0, oa0, 0, 0, 0);
      oa1 = __builtin_amdgcn_mfma_f32_32x32x16_bf16(vf1[0], pf0, oa1, 0, 0, 0);
      const bf16x8 pf1 = packP(sa0[8], sa0[9], sa0[10], sa0[11], sa0[12], sa0[13], sa0[14], sa0[15]);
      oa0 = __builtin_amdgcn_mfma_f32_32x32x16_bf16(vf0[1], pf1, oa0, 0, 0, 0);
      oa1 = __builtin_amdgcn_mfma_f32_32x32x16_bf16(vf1[1], pf1, oa1, 0, 0, 0);
      const bf16x8 pf2 = packP(sa1[0], sa1[1], sa1[2], sa1[3], sa1[4], sa1[5], sa1[6], sa1[7]);
      oa0 = __builtin_amdgcn_mfma_f32_32x32x16_bf16(vf0[2], pf2, oa0, 0, 0, 0);
      oa1 = __builtin_amdgcn_mfma_f32_32x32x16_bf16(vf1[2], pf2, oa1, 0, 0, 0);
      const bf16x8 pf3 = packP(sa1[8], sa1[9], sa1[10], sa1[11], sa1[12], sa1[13], sa1[14], sa1[15]);
      oa0 = __builtin_amdgcn_mfma_f32_32x32x16_bf16(vf0[3], pf3, oa0, 0, 0, 0);
      oa1 = __builtin_amdgcn_mfma_f32_32x32x16_bf16(vf1[3], pf3, oa1, 0, 0, 0);
    }
  }
  const float invl = 1.f / l;
#pragma unroll
  for (int n = 0; n < 2; ++n) {
#pragma unroll
    for (int g = 0; g < 4; ++g) {
      union { ushort4 u4; bf16 bb[4]; } o4;
#pragma unroll
      for (int mi = 0; mi < 4; ++mi) {
        const float val = (n ? oa1[4 * g + mi] : oa0[4 * g + mi]) * invl;
        o4.bb[mi] = __float2bfloat16(val);
      }
      const int d = n * 32 + 8 * g + 4 * hi;
      *(ushort4*)&AO[((size_t)(b * S + qrow0 + q)) * D + h * HD + d] = o4.u4;
    }
  }
}

// ---------------- host launch ----------------
extern "C" void kernel_launch(void* const* d_in, const int* in_sizes, int n_in,
                              void* d_out, int out_size, void* d_ws, size_t ws_size,
                              hipStream_t stream) {
  const float* x = (const float*)d_in[0];
  const int* mt = (const int*)d_in[1];
  const float* rms1 = (const float*)d_in[2];
  const float* wqkv = (const float*)d_in[3];
  const float* wo = (const float*)d_in[4];
  const float* rms2 = (const float*)d_in[5];
  const float* w1 = (const float*)d_in[6];
  const float* w2 = (const float*)d_in[7];
  float* out = (float*)d_out;
  (void)in_sizes; (void)n_in; (void)out_size; (void)ws_size;

  char* ws = (char*)d_ws;
  size_t off = 0;
  auto alloc = [&](size_t b) { void* p = ws + off; off = (off + b + 255) & ~(size_t)255; return p; };
  bf16* wqkvT = (bf16*)alloc((size_t)3072 * 1024 * 2);
  bf16* woT   = (bf16*)alloc((size_t)1024 * 1024 * 2);
  bf16* w1T   = (bf16*)alloc((size_t)E * F * D * 2);
  bf16* w2T   = (bf16*)alloc((size_t)E * D * F * 2);
  float* cosT = (float*)alloc((size_t)S * 32 * 4);
  float* sinT = (float*)alloc((size_t)S * 32 * 4);
  float* hbuf = (float*)alloc((size_t)TOK * D * 4);
  bf16* xn2   = (bf16*)alloc((size_t)TOK * D * 2);  // MoE rmsnorm out (separate from R)
  int* counts  = (int*)alloc(E * 4);
  int* cursors = (int*)alloc(E * 4);
  int* aoff    = (int*)alloc((E + 1) * 4);
  int* perm    = (int*)alloc(SLOTS * 4);
  char* R = (char*)alloc((size_t)5 * TOK * D * 2);  // xn|q|k|vT|ao, later reused as act
  bf16* xn = (bf16*)R;
  bf16* qb = (bf16*)(R + (size_t)1 * TOK * D * 2);
  bf16* kb = (bf16*)(R + (size_t)2 * TOK * D * 2);
  bf16* vb = (bf16*)(R + (size_t)3 * TOK * D * 2);  // Vt [bh][d][s]
  bf16* ao = (bf16*)(R + (size_t)4 * TOK * D * 2);
  bf16* act = (bf16*)R;  // 75.5MB <= 83.9MB; all of R dead by FFN1

  cvt_transpose<<<dim3(3072 / 64, 1024 / 64, 1), 256, 0, stream>>>(wqkv, wqkvT, 1024, 3072);
  cvt_transpose<<<dim3(1024 / 64, 1024 / 64, 1), 256, 0, stream>>>(wo, woT, 1024, 1024);
  cvt_transpose<<<dim3(4096 / 64, 1024 / 64, E), 256, 0, stream>>>(w1, w1T, 1024, 4096);
  cvt_transpose<<<dim3(1024 / 64, 4096 / 64, E), 256, 0, stream>>>(w2, w2T, 4096, 1024);
  rope_tables<<<dim3(S / 2), 64, 0, stream>>>(cosT, sinT);
  route_init<<<dim3((SLOTS + 255) / 256), 256, 0, stream>>>(counts, cursors, perm);
  route_count<<<dim3(TOK / 256), 256, 0, stream>>>(mt, counts);
  route_offsets<<<dim3(1), 64, 0, stream>>>(counts, aoff);
  route_scatter<<<dim3(TOK / 256), 256, 0, stream>>>(mt, aoff, cursors, perm);
  // attention path
  rmsnorm_k<<<dim3(TOK), 256, 0, stream>>>(x, rms1, xn);
  qkv8p<<<dim3(3072 / 256, TOK / 256), 512, 0, stream>>>(
      xn, wqkvT, cosT, sinT, qb, kb, vb);
  attn_kernel<<<dim3(64, S / 64), 128, 0, stream>>>(qb, kb, vb, ao);
  gemm_bt<1, 128><<<dim3(1024 / 128, TOK / 128), 256, 0, stream>>>(  // out-proj
      ao, woT, TOK, 1024, 1024, nullptr, 0, x, hbuf, nullptr, nullptr, nullptr, nullptr);
  // MoE path
  rmsnorm_k<<<dim3(TOK), 256, 0, stream>>>(hbuf, rms2, xn2);
  gemm_bt<2, 128><<<dim3(4096 / 128, SLOTS / 128), 256, 0, stream>>>(  // FFN1 + gather + gelu
      xn2, w1T, SLOTS, 4096, 1024, aoff, (long long)F * D, nullptr, nullptr, act, perm,
      nullptr, nullptr);
  gemm_bt<3, 128><<<dim3(1024 / 128, SLOTS / 128), 256, 0, stream>>>(  // FFN2 + scatter
      act, w2T, SLOTS, 1024, 4096, aoff, (long long)D * F, nullptr, nullptr, nullptr, perm,
      hbuf, out);
}

// Round 4
// 625.563 us; speedup vs baseline: 1.1779x; 1.1168x over previous
//
#include <hip/hip_runtime.h>
#include <hip/hip_bf16.h>
#include <stdint.h>

typedef __hip_bfloat16 bf16;
typedef __attribute__((ext_vector_type(8))) short bf16x8;
typedef __attribute__((ext_vector_type(4))) float f32x4;
typedef __attribute__((ext_vector_type(16))) float f32x16;
typedef unsigned int u32;

static constexpr int Bsz = 4, S = 2048, D = 1024, E = 8, F = 4096, NH = 16, HD = 64;
static constexpr int TOK = Bsz * S;          // 8192 tokens
static constexpr int SLOTS = TOK + E * 128;  // 9216 padded routing slots (128-aligned experts)

#define DEV __device__ __forceinline__

DEV void async16(const bf16* g, bf16* l) {
  __builtin_amdgcn_global_load_lds((const __attribute__((address_space(1))) u32*)g,
                                   (__attribute__((address_space(3))) u32*)l, 16, 0, 0);
}

DEV u32 lds_off(const bf16* p) {
  return (u32)(uintptr_t)(__attribute__((address_space(3))) bf16*)p;
}

DEV bf16x8 dsr128(u32 addr) {  // asm ds_read: invisible to LDS alias analysis
  bf16x8 d;
  asm volatile("ds_read_b128 %0, %1" : "=v"(d) : "v"(addr));
  return d;
}

// gelu(x) = 0.5x(1+tanh(z)) = x * sigmoid(2z)
DEV float gelu_fast(float x) {
  const float z = 0.7978845608028654f * (x + 0.044715f * x * x * x);
  return x / (1.f + __expf(-2.f * z));
}

DEV u32 cvtpk(float lo, float hi) {  // word = (bf16(lo), bf16(hi)) packed
  u32 r;
  asm("v_cvt_pk_bf16_f32 %0, %1, %2" : "=v"(r) : "v"(lo), "v"(hi));
  return r;
}

// ---------------- small kernels ----------------

// fp32 [R][C] -> bf16 [C][R], 64x64 tiles: 16B/lane coalesced on BOTH sides
__global__ void cvt_transpose(const float* __restrict__ in, bf16* __restrict__ out, int R, int C) {
  __shared__ float t[64][65];
  const size_t zoff = (size_t)blockIdx.z * R * C;
  const int c0 = blockIdx.x * 64, r0 = blockIdx.y * 64;
  const int tid = threadIdx.x;
  const int lrow = tid >> 4, lcol = (tid & 15) * 4;
#pragma unroll
  for (int p = 0; p < 4; ++p) {
    const int r = lrow + p * 16;
    const float4 v = *(const float4*)(in + zoff + (size_t)(r0 + r) * C + c0 + lcol);
    t[r][lcol] = v.x; t[r][lcol + 1] = v.y; t[r][lcol + 2] = v.z; t[r][lcol + 3] = v.w;
  }
  __syncthreads();
  const int ow = tid >> 3, je = (tid & 7) * 8;
#pragma unroll
  for (int p = 0; p < 2; ++p) {
    const int oc = ow + p * 32;
    union { bf16x8 v; bf16 b[8]; } o8;
#pragma unroll
    for (int j = 0; j < 8; ++j) o8.b[j] = __float2bfloat16(t[je + j][oc]);
    *(bf16x8*)(out + zoff + (size_t)(c0 + oc) * R + r0 + je) = o8.v;
  }
}

__global__ void rope_tables(float* __restrict__ cosT, float* __restrict__ sinT) {
  const int s = blockIdx.x * 2 + (threadIdx.x >> 5);
  const int i = threadIdx.x & 31;
  const float inv_freq = powf(10000.f, -(float)i / 32.f);
  const float ang = (float)s * inv_freq;
  cosT[s * 32 + i] = cosf(ang);
  sinT[s * 32 + i] = sinf(ang);
}

__global__ void rmsnorm_k(const float* __restrict__ x, const float* __restrict__ w, bf16* __restrict__ out) {
  const size_t row = blockIdx.x;
  const int tid = threadIdx.x;
  const float4 v = *(const float4*)(x + row * D + tid * 4);
  float ss = v.x * v.x + v.y * v.y + v.z * v.z + v.w * v.w;
#pragma unroll
  for (int off = 1; off < 64; off <<= 1) ss += __shfl_xor(ss, off);
  __shared__ float red[4];
  if ((tid & 63) == 0) red[tid >> 6] = ss;
  __syncthreads();
  const float inv = rsqrtf((red[0] + red[1] + red[2] + red[3]) * (1.f / D) + 1e-6f);
  const float4 wv = *(const float4*)(w + tid * 4);
  union { ushort4 u; bf16 b[4]; } o;
  o.b[0] = __float2bfloat16(v.x * inv * wv.x);
  o.b[1] = __float2bfloat16(v.y * inv * wv.y);
  o.b[2] = __float2bfloat16(v.z * inv * wv.z);
  o.b[3] = __float2bfloat16(v.w * inv * wv.w);
  *(ushort4*)((unsigned short*)out + row * D + tid * 4) = o.u;
}

// ---------------- routing ----------------
__global__ void route_init(int* counts, int* cursors, int* perm) {
  const int i = blockIdx.x * 256 + threadIdx.x;
  if (i < E) { counts[i] = 0; cursors[i] = 0; }
  if (i < SLOTS) perm[i] = -1;
}
__global__ void route_count(const int* __restrict__ mt, int* counts) {
  const int i = blockIdx.x * 256 + threadIdx.x;
  if (i < TOK) atomicAdd(&counts[mt[i]], 1);
}
__global__ void route_offsets(const int* __restrict__ counts, int* aoff) {
  if (threadIdx.x == 0) {
    int off = 0; aoff[0] = 0;
    for (int e = 0; e < E; ++e) { off += (counts[e] + 127) & ~127; aoff[e + 1] = off; }
  }
}
__global__ void route_scatter(const int* __restrict__ mt, const int* __restrict__ aoff,
                              int* cursors, int* perm) {
  const int i = blockIdx.x * 256 + threadIdx.x;
  if (i < TOK) { const int e = mt[i]; perm[aoff[e] + atomicAdd(&cursors[e], 1)] = i; }
}

// -------- QKV GEMM: 4-phase/tile counted-vmcnt pipeline (r13-proven, verbatim) --------
__global__ __launch_bounds__(512) void qkv8p(
    const bf16* __restrict__ A, const bf16* __restrict__ Bt,
    const float* __restrict__ c_t, const float* __restrict__ s_t,
    bf16* __restrict__ o_q, bf16* __restrict__ o_k, bf16* __restrict__ o_v) {
  constexpr int K = 1024, NT = K / 64;
  __shared__ __align__(16) bf16 LA[2][256 * 64];
  __shared__ __align__(16) bf16 LB[2][256 * 64];
  const int tid = threadIdx.x;
  const int lane = tid & 63, wv = tid >> 6;
  const int wm = wv >> 2, wn = wv & 3;
  const int rl = lane & 15, kg = lane >> 4;
  const int gx = gridDim.x;               // 12
  const int nwg = gx * gridDim.y;         // 384 (%8==0)
  int bid = blockIdx.y * gx + blockIdx.x;
  bid = (bid & 7) * (nwg >> 3) + (bid >> 3);
  const int nbase = (bid % gx) * 256, mbase = (bid / gx) * 256;
  f32x4 acc[8][4] = {};
  const int srow = tid >> 3;
  const int sc = (tid & 7) ^ ((srow >> 1) & 7);
  const bf16* Ag = A + (size_t)(mbase + srow) * K + sc * 8;
  const bf16* Bg = Bt + (size_t)(nbase + srow) * K + sc * 8;

  auto stage = [&](int t, int h) {  // h: 0=A-lo 1=A-hi 2=B-lo 3=B-hi
    const int buf = t & 1;
    const int mat = h >> 1, rh = h & 1;
    const bf16* src = (mat ? Bg : Ag) + (size_t)(rh * 128) * K + t * 64;
    bf16* dst = (mat ? &LB[buf][0] : &LA[buf][0]) + rh * 128 * 64 + tid * 8;
    async16(src, dst);
    async16(src + (size_t)64 * K, dst + 64 * 64);
  };

  bf16x8 bfr[4];
  auto phaseC = [&](int t, int ks, int mih, bool loadB) {
    const int buf = t & 1;
    const u32 ab = lds_off(&LA[buf][0]);
    const u32 bb = lds_off(&LB[buf][0]);
    bf16x8 af[4];
#pragma unroll
    for (int mi = 0; mi < 4; ++mi) {
      const int row = wm * 128 + mih * 64 + mi * 16 + rl;
      const u32 ph = (u32)((ks * 4 + kg) ^ ((row >> 1) & 7));
      af[mi] = dsr128(ab + (u32)row * 128 + ph * 16);
    }
    if (loadB) {
#pragma unroll
      for (int ni = 0; ni < 4; ++ni) {
        const int row = wn * 64 + ni * 16 + rl;
        const u32 ph = (u32)((ks * 4 + kg) ^ ((row >> 1) & 7));
        bfr[ni] = dsr128(bb + (u32)row * 128 + ph * 16);
      }
    }
    asm volatile("s_waitcnt lgkmcnt(0)" ::: "memory");
    __builtin_amdgcn_sched_barrier(0);
    __builtin_amdgcn_s_setprio(1);
#pragma unroll
    for (int mi = 0; mi < 4; ++mi)
#pragma unroll
      for (int ni = 0; ni < 4; ++ni)
        acc[mih * 4 + mi][ni] =
            __builtin_amdgcn_mfma_f32_16x16x32_bf16(af[mi], bfr[ni], acc[mih * 4 + mi][ni], 0, 0, 0);
    __builtin_amdgcn_s_setprio(0);
  };

  stage(0, 0); stage(0, 1); stage(0, 2); stage(0, 3);
  for (int t = 0; t < NT; ++t) {
    const bool more = (t + 1 < NT);
#pragma unroll
    for (int p = 0; p < 4; ++p) {
      if (p == 0) {
        if (more) {
          stage(t + 1, 0);
          asm volatile("s_waitcnt vmcnt(2)" ::: "memory");
        } else {
          asm volatile("s_waitcnt vmcnt(0)" ::: "memory");
        }
        __builtin_amdgcn_s_barrier();
        __builtin_amdgcn_sched_barrier(0);
      } else if (more) {
        stage(t + 1, p);
      }
      phaseC(t, p >> 1, p & 1, (p & 1) == 0);
      __builtin_amdgcn_s_barrier();
      __builtin_amdgcn_sched_barrier(0);
    }
  }

  const int colbase = nbase + wn * 64;
  const int part = colbase >> 10;
  const int head = (colbase & 1023) >> 6;
  const float qs = (part == 0) ? 0.18033688011112042f : 1.f;  // fold 0.125*log2e into Q
#pragma unroll
  for (int ai = 0; ai < 8; ++ai) {
    const int rowoff = (ai >> 2) * 64 + (ai & 3) * 16;
#pragma unroll
    for (int r = 0; r < 4; ++r) {
      const int grow = mbase + wm * 128 + rowoff + kg * 4 + r;
      const int bb = grow >> 11, sp = grow & (S - 1);
      if (part == 2) {
#pragma unroll
        for (int ni = 0; ni < 4; ++ni) {
          const int d = ni * 16 + rl;
          o_v[((size_t)(bb * NH + head) * HD + d) * S + sp] = __float2bfloat16(acc[ai][ni][r]);
        }
      } else {
        bf16* dst = (part == 0) ? o_q : o_k;
        const size_t base = ((size_t)(bb * NH + head) * S + sp) * HD;
#pragma unroll
        for (int np = 0; np < 2; ++np) {
          const int i = np * 16 + rl;
          const float c = c_t[sp * 32 + i];
          const float sn = s_t[sp * 32 + i];
          const float lo = acc[ai][np][r];
          const float hi = acc[ai][np + 2][r];
          dst[base + i] = __float2bfloat16((lo * c - hi * sn) * qs);
          dst[base + i + 32] = __float2bfloat16((hi * c + lo * sn) * qs);
        }
      }
    }
  }
}

// ---------------- GEMM: C = A[M,K] * Bt[N,K]^T (r11/r14/r16-proven 2-phase) ----------------
// EPI 1: h = x + acc.  EPI 2: FFN1 + fused gather, act=gelu.  EPI 3: out[perm] = h + acc.
template <int EPI, int BM>
__global__ __launch_bounds__(2 * BM) void gemm_bt(
    const bf16* __restrict__ A, const bf16* __restrict__ Bt, int M, int N, int K,
    const int* __restrict__ aoff, long long estride,
    const float* __restrict__ xres, float* __restrict__ o_h,
    bf16* __restrict__ o_act,
    const int* __restrict__ perm, const float* __restrict__ hres, float* __restrict__ o_out) {
  constexpr int WN = BM / 64;
  constexpr int MR = BM / 2;
  constexpr int M_FR = MR / 16;
  __shared__ __align__(16) bf16 As[2][BM * 32];
  __shared__ __align__(16) bf16 Bs[2][BM * 32];
  const int tid = threadIdx.x;
  const int lane = tid & 63, wv = tid >> 6;
  const int wm = wv / WN, wn = wv % WN;
  const int rl = lane & 15, kg = lane >> 4;
  const int gx = gridDim.x;
  const int nwg = gx * gridDim.y;
  int bid = blockIdx.y * gx + blockIdx.x;
  bid = (bid & 7) * (nwg >> 3) + (bid >> 3);
  const int nbase = (bid % gx) * BM, mbase = (bid / gx) * BM;
  const bf16* Btp = Bt;
  if constexpr (EPI >= 2) {
    int e = 0;
#pragma unroll
    for (int t = 0; t < E - 1; ++t) e += (mbase >= aoff[t + 1]) ? 1 : 0;
    Btp = Bt + (size_t)e * estride;
  }
  f32x4 acc[M_FR][4] = {};
  const int srow = tid >> 2;
  const int sc = (tid & 3) ^ ((srow >> 1) & 3);
  const bf16* Agp[2];
#pragma unroll
  for (int c = 0; c < 2; ++c) {
    int rowslot = mbase + c * MR + srow;
    if constexpr (EPI == 2) {
      const int t = perm[rowslot];
      rowslot = (t < 0) ? 0 : t;
    }
    Agp[c] = A + (size_t)rowslot * K + sc * 8;
  }
  const bf16* Bg = Btp + (size_t)(nbase + srow) * K + sc * 8;

  auto stage = [&](int bi, int ko) {
#pragma unroll
    for (int c = 0; c < 2; ++c) {
      async16(Agp[c] + ko, &As[bi][c * MR * 32 + wv * 512]);
      async16(Bg + (size_t)(c * MR) * K + ko, &Bs[bi][c * MR * 32 + wv * 512]);
    }
  };
  auto compute = [&](int bi) {
    bf16x8 af[M_FR], bfr[4];
#pragma unroll
    for (int mi = 0; mi < M_FR; ++mi) {
      const int row = wm * MR + mi * 16 + rl;
      af[mi] = *(const bf16x8*)&As[bi][row * 32 + ((kg ^ ((row >> 1) & 3))) * 8];
    }
#pragma unroll
    for (int ni = 0; ni < 4; ++ni) {
      const int row = wn * 64 + ni * 16 + rl;
      bfr[ni] = *(const bf16x8*)&Bs[bi][row * 32 + ((kg ^ ((row >> 1) & 3))) * 8];
    }
#pragma unroll
    for (int mi = 0; mi < M_FR; ++mi)
#pragma unroll
      for (int ni = 0; ni < 4; ++ni)
        acc[mi][ni] = __builtin_amdgcn_mfma_f32_16x16x32_bf16(af[mi], bfr[ni], acc[mi][ni], 0, 0, 0);
  };

  const int nk = K >> 5;
  stage(0, 0);
  __syncthreads();
  for (int kb = 0; kb < nk; ++kb) {
    if (kb + 1 < nk) stage((kb + 1) & 1, (kb + 1) * 32);
    compute(kb & 1);
    __syncthreads();
  }

#pragma unroll
  for (int mi = 0; mi < M_FR; ++mi) {
#pragma unroll
    for (int ni = 0; ni < 4; ++ni) {
#pragma unroll
      for (int r = 0; r < 4; ++r) {
        const int grow = mbase + wm * MR + mi * 16 + kg * 4 + r;
        const int gcol = nbase + wn * 64 + ni * 16 + rl;
        const float vv = acc[mi][ni][r];
        if constexpr (EPI == 1) {
          const size_t ix = (size_t)grow * 1024 + gcol;
          o_h[ix] = xres[ix] + vv;
        } else if constexpr (EPI == 2) {
          o_act[(size_t)grow * 4096 + gcol] = __float2bfloat16(gelu_fast(vv));
        } else {
          const int t = perm[grow];
          if (t >= 0) {
            const size_t ix = (size_t)t * 1024 + gcol;
            o_out[ix] = hres[ix] + vv;
          }
        }
      }
    }
  }
}

// ------- flash attention: 4-wave block, Q=128 rows, K/V LDS-staged per 64-kv tile -------
// Q pre-scaled by 0.125*log2e. Swapped-operand 32x32 QK; P transposed in-register via
// cvt_pk + permlane32_swap. K/V staged coalesced via global_load_lds with pre-swizzled
// source chunks (chunk ^= row&7) so linear LDS writes + XOR'd reads are conflict-light.
__global__ __launch_bounds__(256, 3) void attn_kernel(const bf16* __restrict__ Qb,
                                                      const bf16* __restrict__ Kb,
                                                      const bf16* __restrict__ Vt,
                                                      bf16* __restrict__ AO) {
  __shared__ __align__(16) bf16 Kl[2][64 * 64];
  __shared__ __align__(16) bf16 Vl[2][64 * 64];
  const int bh = blockIdx.x;  // x fastest => XCD = bh % 8; all q-blocks of a head on one XCD
  const int tid = threadIdx.x;
  const int w = tid >> 6, lane = tid & 63;
  const int q = lane & 31, hi = lane >> 5;
  const bf16* Qp = Qb + (size_t)bh * S * HD;
  const bf16* Kp = Kb + (size_t)bh * S * HD;
  const bf16* Vp = Vt + (size_t)bh * S * HD;  // [HD][S]
  const int b = bh >> 4, h = bh & 15;
  const int qblk = (S / 128 - 1) - blockIdx.y;  // heaviest first
  const int qrow0 = qblk * 128 + w * 32;
  const int ntb = qblk * 2 + 2;        // block-wide kv tiles (covers rows < qblk*128+128)
  const int ntw = (qrow0 >> 6) + 1;    // this wave's causal tile count
  const int srow = tid >> 3;           // staging: 32 rows per half
  const int schk = tid & 7;

  bf16x8 qf[4];
#pragma unroll
  for (int t = 0; t < 4; ++t)
    qf[t] = *(const bf16x8*)(Qp + (size_t)(qrow0 + q) * HD + t * 16 + hi * 8);
  f32x16 oa0 = {}, oa1 = {};
  float m = -INFINITY, l = 0.f;

  auto stageKV = [&](int buf, int kvb) {
#pragma unroll
    for (int hh = 0; hh < 2; ++hh) {
      const int row = srow + hh * 32;
      const int c = schk ^ (row & 7);  // pre-swizzle source so linear LDS write + XOR read match
      async16(Kp + (size_t)(kvb + row) * HD + c * 8, &Kl[buf][tid * 8 + hh * 2048]);
      async16(Vp + (size_t)row * S + kvb + c * 8, &Vl[buf][tid * 8 + hh * 2048]);
    }
  };
  // pf(lane q,hi) element j = P[k = 16*s2i + 8*hi + j][q]; source sa[r]: k=(r&3)+8*(r>>2)+4*hi.
  auto packP = [&](float s0, float s1, float s2, float s3,
                   float s4, float s5, float s6, float s7) -> bf16x8 {
    u32 x0 = cvtpk(s0, s1), x1 = cvtpk(s2, s3);
    u32 y0 = cvtpk(s4, s5), y1 = cvtpk(s6, s7);
    asm volatile("v_permlane32_swap_b32 %0, %1" : "+v"(x0), "+v"(y0));
    asm volatile("v_permlane32_swap_b32 %0, %1" : "+v"(x1), "+v"(y1));
    union { u32 w[4]; bf16x8 v; } u;
    u.w[0] = x0; u.w[1] = x1; u.w[2] = y0; u.w[3] = y1;
    return u.v;
  };

  stageKV(0, 0);
  __syncthreads();
  for (int kt = 0; kt < ntb; ++kt) {
    const int buf = kt & 1;
    const int kvb = kt * 64;
    if (kt + 1 < ntb) stageKV(buf ^ 1, kvb + 64);  // issue early; end-of-loop barrier drains
    if (kt < ntw) {
      f32x16 sa0 = {}, sa1 = {};
#pragma unroll
      for (int t = 0; t < 4; ++t) {
        const int c = (2 * t + hi) ^ (q & 7);
        const bf16x8 kf0 = *(const bf16x8*)&Kl[buf][q * 64 + c * 8];
        sa0 = __builtin_amdgcn_mfma_f32_32x32x16_bf16(kf0, qf[t], sa0, 0, 0, 0);
      }
#pragma unroll
      for (int t = 0; t < 4; ++t) {
        const int c = (2 * t + hi) ^ (q & 7);  // (q+32)&7 == q&7
        const bf16x8 kf1 = *(const bf16x8*)&Kl[buf][(q + 32) * 64 + c * 8];
        sa1 = __builtin_amdgcn_mfma_f32_32x32x16_bf16(kf1, qf[t], sa1, 0, 0, 0);
      }
      if (kvb + 63 > qrow0) {  // only diagonal/edge tiles need masking
#pragma unroll
        for (int r = 0; r < 16; ++r) {
          const int kloc = (r & 3) + 8 * (r >> 2) + 4 * hi;
          sa0[r] = (kvb + kloc > qrow0 + q) ? -3.0e38f : sa0[r];
          sa1[r] = (kvb + 32 + kloc > qrow0 + q) ? -3.0e38f : sa1[r];
        }
      }
      float vm;
      {
        float a0 = fmaxf(fmaxf(sa0[0], sa0[1]), fmaxf(sa0[2], sa0[3]));
        float a1 = fmaxf(fmaxf(sa0[4], sa0[5]), fmaxf(sa0[6], sa0[7]));
        float a2 = fmaxf(fmaxf(sa0[8], sa0[9]), fmaxf(sa0[10], sa0[11]));
        float a3 = fmaxf(fmaxf(sa0[12], sa0[13]), fmaxf(sa0[14], sa0[15]));
        float b0 = fmaxf(fmaxf(sa1[0], sa1[1]), fmaxf(sa1[2], sa1[3]));
        float b1 = fmaxf(fmaxf(sa1[4], sa1[5]), fmaxf(sa1[6], sa1[7]));
        float b2 = fmaxf(fmaxf(sa1[8], sa1[9]), fmaxf(sa1[10], sa1[11]));
        float b3 = fmaxf(fmaxf(sa1[12], sa1[13]), fmaxf(sa1[14], sa1[15]));
        vm = fmaxf(fmaxf(fmaxf(a0, a1), fmaxf(a2, a3)), fmaxf(fmaxf(b0, b1), fmaxf(b2, b3)));
      }
      vm = fmaxf(vm, __shfl_xor(vm, 32));
      const bool grow = __any(vm > m);  // T13 (exact)
      const float mn = grow ? fmaxf(m, vm) : m;
#pragma unroll
      for (int r = 0; r < 16; ++r) {
        sa0[r] = exp2f(sa0[r] - mn);
        sa1[r] = exp2f(sa1[r] - mn);
      }
      float ps;
      {
        float a0 = (sa0[0] + sa0[1]) + (sa0[2] + sa0[3]);
        float a1 = (sa0[4] + sa0[5]) + (sa0[6] + sa0[7]);
        float a2 = (sa0[8] + sa0[9]) + (sa0[10] + sa0[11]);
        float a3 = (sa0[12] + sa0[13]) + (sa0[14] + sa0[15]);
        float b0 = (sa1[0] + sa1[1]) + (sa1[2] + sa1[3]);
        float b1 = (sa1[4] + sa1[5]) + (sa1[6] + sa1[7]);
        float b2 = (sa1[8] + sa1[9]) + (sa1[10] + sa1[11]);
        float b3 = (sa1[12] + sa1[13]) + (sa1[14] + sa1[15]);
        ps = ((a0 + a1) + (a2 + a3)) + ((b0 + b1) + (b2 + b3));
      }
      ps += __shfl_xor(ps, 32);
      if (grow) {
        const float scs = exp2f(m - mn);
        l = l * scs + ps;
        m = mn;
#pragma unroll
        for (int r = 0; r < 16; ++r) { oa0[r] *= scs; oa1[r] *= scs; }
      } else {
        l += ps;
      }
      {
        auto vrd = [&](int r, int s2i) -> bf16x8 {
          const int c = (2 * s2i + hi) ^ (r & 7);
          return *(const bf16x8*)&Vl[buf][r * 64 + c * 8];
        };
        const bf16x8 pf0 = packP(sa0[0], sa0[1], sa0[2], sa0[3], sa0[4], sa0[5], sa0[6], sa0[7]);
        oa0 = __builtin_amdgcn_mfma_f32_32x32x16_bf16(vrd(q, 0), pf0, oa0, 0, 0, 0);
        oa1 = __builtin_amdgcn_mfma_f32_32x32x16_bf16(vrd(q + 32, 0), pf0, oa1, 0, 0, 0);
        const bf16x8 pf1 = packP(sa0[8], sa0[9], sa0[10], sa0[11], sa0[12], sa0[13], sa0[14], sa0[15]);
        oa0 = __builtin_amdgcn_mfma_f32_32x32x16_bf16(vrd(q, 1), pf1, oa0, 0, 0, 0);
        oa1 = __builtin_amdgcn_mfma_f32_32x32x16_bf16(vrd(q + 32, 1), pf1, oa1, 0, 0, 0);
        const bf16x8 pf2 = packP(sa1[0], sa1[1], sa1[2], sa1[3], sa1[4], sa1[5], sa1[6], sa1[7]);
        oa0 = __builtin_amdgcn_mfma_f32_32x32x16_bf16(vrd(q, 2), pf2, oa0, 0, 0, 0);
        oa1 = __builtin_amdgcn_mfma_f32_32x32x16_bf16(vrd(q + 32, 2), pf2, oa1, 0, 0, 0);
        const bf16x8 pf3 = packP(sa1[8], sa1[9], sa1[10], sa1[11], sa1[12], sa1[13], sa1[14], sa1[15]);
        oa0 = __builtin_amdgcn_mfma_f32_32x32x16_bf16(vrd(q, 3), pf3, oa0, 0, 0, 0);
        oa1 = __builtin_amdgcn_mfma_f32_32x32x16_bf16(vrd(q + 32, 3), pf3, oa1, 0, 0, 0);
      }
    }
    __syncthreads();  // drains next-tile staging loads; guards LDS buffer reuse
  }
  const float invl = 1.f / l;
#pragma unroll
  for (int n = 0; n < 2; ++n) {
#pragma unroll
    for (int g = 0; g < 4; ++g) {
      union { ushort4 u4; bf16 bb[4]; } o4;
#pragma unroll
      for (int mi = 0; mi < 4; ++mi) {
        const float val = (n ? oa1[4 * g + mi] : oa0[4 * g + mi]) * invl;
        o4.bb[mi] = __float2bfloat16(val);
      }
      const int d = n * 32 + 8 * g + 4 * hi;
      *(ushort4*)&AO[((size_t)(b * S + qrow0 + q)) * D + h * HD + d] = o4.u4;
    }
  }
}

// ---------------- host launch ----------------
extern "C" void kernel_launch(void* const* d_in, const int* in_sizes, int n_in,
                              void* d_out, int out_size, void* d_ws, size_t ws_size,
                              hipStream_t stream) {
  const float* x = (const float*)d_in[0];
  const int* mt = (const int*)d_in[1];
  const float* rms1 = (const float*)d_in[2];
  const float* wqkv = (const float*)d_in[3];
  const float* wo = (const float*)d_in[4];
  const float* rms2 = (const float*)d_in[5];
  const float* w1 = (const float*)d_in[6];
  const float* w2 = (const float*)d_in[7];
  float* out = (float*)d_out;
  (void)in_sizes; (void)n_in; (void)out_size; (void)ws_size;

  char* ws = (char*)d_ws;
  size_t off = 0;
  auto alloc = [&](size_t b) { void* p = ws + off; off = (off + b + 255) & ~(size_t)255; return p; };
  bf16* wqkvT = (bf16*)alloc((size_t)3072 * 1024 * 2);
  bf16* woT   = (bf16*)alloc((size_t)1024 * 1024 * 2);
  bf16* w1T   = (bf16*)alloc((size_t)E * F * D * 2);
  bf16* w2T   = (bf16*)alloc((size_t)E * D * F * 2);
  float* cosT = (float*)alloc((size_t)S * 32 * 4);
  float* sinT = (float*)alloc((size_t)S * 32 * 4);
  float* hbuf = (float*)alloc((size_t)TOK * D * 4);
  bf16* xn2   = (bf16*)alloc((size_t)TOK * D * 2);  // MoE rmsnorm out (separate from R)
  int* counts  = (int*)alloc(E * 4);
  int* cursors = (int*)alloc(E * 4);
  int* aoff    = (int*)alloc((E + 1) * 4);
  int* perm    = (int*)alloc(SLOTS * 4);
  char* R = (char*)alloc((size_t)5 * TOK * D * 2);  // xn|q|k|vT|ao, later reused as act
  bf16* xn = (bf16*)R;
  bf16* qb = (bf16*)(R + (size_t)1 * TOK * D * 2);
  bf16* kb = (bf16*)(R + (size_t)2 * TOK * D * 2);
  bf16* vb = (bf16*)(R + (size_t)3 * TOK * D * 2);  // Vt [bh][d][s]
  bf16* ao = (bf16*)(R + (size_t)4 * TOK * D * 2);
  bf16* act = (bf16*)R;  // 75.5MB <= 83.9MB; all of R dead by FFN1

  cvt_transpose<<<dim3(3072 / 64, 1024 / 64, 1), 256, 0, stream>>>(wqkv, wqkvT, 1024, 3072);
  cvt_transpose<<<dim3(1024 / 64, 1024 / 64, 1), 256, 0, stream>>>(wo, woT, 1024, 1024);
  cvt_transpose<<<dim3(4096 / 64, 1024 / 64, E), 256, 0, stream>>>(w1, w1T, 1024, 4096);
  cvt_transpose<<<dim3(1024 / 64, 4096 / 64, E), 256, 0, stream>>>(w2, w2T, 4096, 1024);
  rope_tables<<<dim3(S / 2), 64, 0, stream>>>(cosT, sinT);
  route_init<<<dim3((SLOTS + 255) / 256), 256, 0, stream>>>(counts, cursors, perm);
  route_count<<<dim3(TOK / 256), 256, 0, stream>>>(mt, counts);
  route_offsets<<<dim3(1), 64, 0, stream>>>(counts, aoff);
  route_scatter<<<dim3(TOK / 256), 256, 0, stream>>>(mt, aoff, cursors, perm);
  // attention path
  rmsnorm_k<<<dim3(TOK), 256, 0, stream>>>(x, rms1, xn);
  qkv8p<<<dim3(3072 / 256, TOK / 256), 512, 0, stream>>>(
      xn, wqkvT, cosT, sinT, qb, kb, vb);
  attn_kernel<<<dim3(64, S / 128), 256, 0, stream>>>(qb, kb, vb, ao);
  gemm_bt<1, 128><<<dim3(1024 / 128, TOK / 128), 256, 0, stream>>>(  // out-proj
      ao, woT, TOK, 1024, 1024, nullptr, 0, x, hbuf, nullptr, nullptr, nullptr, nullptr);
  // MoE path
  rmsnorm_k<<<dim3(TOK), 256, 0, stream>>>(hbuf, rms2, xn2);
  gemm_bt<2, 128><<<dim3(4096 / 128, SLOTS / 128), 256, 0, stream>>>(  // FFN1 + gather + gelu
      xn2, w1T, SLOTS, 4096, 1024, aoff, (long long)F * D, nullptr, nullptr, act, perm,
      nullptr, nullptr);
  gemm_bt<3, 128><<<dim3(1024 / 128, SLOTS / 128), 256, 0, stream>>>(  // FFN2 + scatter
      act, w2T, SLOTS, 1024, 4096, aoff, (long long)D * F, nullptr, nullptr, nullptr, perm,
      hbuf, out);
}